// Round 7
// baseline (305.316 us; speedup 1.0000x reference)
//
#include <hip/hip_runtime.h>
#include <math.h>

#define NCLS 20
#define HALFC 10
#define IGNORE_IDX 255
#define LOG2E 1.4426950408889634f
#define NTHR 256
#define NBLK 2048
#define NSLOT 32  // global partial-sum slots

typedef float v2f __attribute__((ext_vector_type(2)));
typedef int v2i __attribute__((ext_vector_type(2)));

__device__ __forceinline__ float wave_reduce(float v) {
#pragma unroll
  for (int off = 32; off > 0; off >>= 1) v += __shfl_xor(v, off, 64);
  return v;
}

__device__ __forceinline__ float neg_log_clamped(float x, bool cond) {
  if (!cond) return 0.0f;
  float xs = fmaxf(x, 1e-38f);
  return fminf(-logf(xs), 100.0f);
}

// Layout of s_acc rows / ws columns: [0..19] sum_p, [20..39] nominator,
// [40..59] ct_count, [60..63] unused.
//
// r7 design notes — the waves-law:
//  - Fitting r0/r3/r4 + m13 copy: delivered bytes/s/CU ~= waves/CU x 0.5KB
//    / 600ns, INDEPENDENT of per-wave batch depth (r0's 20-deep batch at
//    7.4 waves = 0.57KB/wave eff; r3's 4-deep at 19.6 waves = 0.57KB/wave;
//    m13's full-occupancy copy = 0.46KB/wave at 24.6 GB/s/CU). BW is bought
//    with WAVES. All prior rounds fought batch depth/registers instead.
//  - So: target 32 waves/CU (VGPR<=64, LDS small), read pred exactly once.
//  - Class-split across half-waves: lane L owns classes (L>>5)*10..+9 of
//    voxel-pair (L&31); partner lane L^32 owns the other 10. e[10] as v2f
//    = 20 VGPRs. Z combined via ONE shfl_xor(32) per voxel — the only
//    cross-lane op. No per-class arrays beyond e[10], no LDS scratch.
//  - sum_p: one fire-and-forget ds_add per class-half into s_acc[c][tid&31]
//    (rows 128B apart -> same bank, different address: 2-way = free, m136).
//    nominator/ct_count added only by the half-wave owning class t.
//  - launch_bounds(256,8) enforces the 64-VGPR/32-wave regime (est. live
//    ~52 -> no spill). LDS = s_acc only, 7.68KB -> 8 blocks/CU resident.
__global__ __launch_bounds__(NTHR, 8) void pass1(const float* __restrict__ pred,
                                                 const int* __restrict__ target,
                                                 float* __restrict__ ws, int N,
                                                 int iters) {
  __shared__ float s_acc[3 * NCLS][32];
  const int tid = threadIdx.x;
  const int lane = tid & 63;
  const int sl = tid & 31;
  const int c0 = (lane >> 5) * HALFC;  // class base for this half-wave
  const int wid = tid >> 6;
  const int npair = N >> 1;

  {
    float* p = &s_acc[0][0];
    for (int i = tid; i < 3 * NCLS * 32; i += NTHR) p[i] = 0.0f;
  }
  __syncthreads();

  for (int k = 0; k < iters; ++k) {
    // lane L and L^32 get the SAME pair (same wid, same sl) -> shfl partner
    const int pair = (k * NBLK + (int)blockIdx.x) * (NTHR >> 1) + wid * 32 + sl;
    const bool inb = (pair < npair);

    v2f e[HALFC];
#pragma unroll
    for (int i = 0; i < HALFC; ++i) e[i] = (v2f)(0.0f);
    v2i t2 = {IGNORE_IDX, IGNORE_IDX};
    v2f Z = (v2f)(0.0f), pt = (v2f)(0.0f);

    if (inb) {
      const int n = pair << 1;
      t2 = *reinterpret_cast<const v2i*>(target + n);
#pragma unroll
      for (int i = 0; i < HALFC; ++i) {
        const v2f x =
            *reinterpret_cast<const v2f*>(pred + (size_t)(c0 + i) * N + n);
#pragma unroll
        for (int j = 0; j < 2; ++j) {
          e[i][j] = __builtin_amdgcn_exp2f(fminf(x[j], 80.0f) * LOG2E);
          Z[j] += e[i][j];
          pt[j] = (c0 + i == t2[j]) ? e[i][j] : pt[j];
        }
      }
    }

    // full Z = my 10-class partial + partner half-wave's partial
    float w[2];
#pragma unroll
    for (int j = 0; j < 2; ++j) {
      const float Zf = Z[j] + __shfl_xor(Z[j], 32, 64);  // uniform exec
      const bool val = inb && (t2[j] != IGNORE_IDX);
      w[j] = val ? __builtin_amdgcn_rcpf(Zf) : 0.0f;
    }

    // sum_p: one ds_add per class-half. Rows 0..9 (lanes<32) and 10..19
    // (lanes>=32), slot=sl -> 2-way same-bank/diff-addr = free. !inb or
    // masked voxels contribute 0 (e=0 or w=0).
#pragma unroll
    for (int i = 0; i < HALFC; ++i)
      atomicAdd(&s_acc[c0 + i][sl], e[i][0] * w[0] + e[i][1] * w[1]);

    // nominator / ct_count: only the half-wave owning class t adds.
#pragma unroll
    for (int j = 0; j < 2; ++j) {
      const int to = t2[j] - c0;
      const bool val = inb && (t2[j] != IGNORE_IDX);
      if (val && to >= 0 && to < HALFC) {
        atomicAdd(&s_acc[NCLS + t2[j]][sl], pt[j] * w[j]);
        atomicAdd(&s_acc[2 * NCLS + t2[j]][sl], 1.0f);
      }
    }
  }
  __syncthreads();

  // block flush: 60 rows x 32 slots, rotated start -> distinct banks/lane.
  if (tid < 3 * NCLS) {
    const float* row = s_acc[tid];
    float v = 0.0f;
#pragma unroll
    for (int i = 0; i < 32; ++i) v += row[(i + tid) & 31];
    // relaxed global atomics; pass2 is a separate dispatch (kernel boundary
    // provides visibility). 32 slots -> chains of NBLK/32 per address.
    atomicAdd(&ws[(size_t)(blockIdx.x & (NSLOT - 1)) * 64 + tid], v);
  }
}

__global__ __launch_bounds__(64) void pass2(const float* __restrict__ ws,
                                            float* __restrict__ out) {
  __shared__ float s[64];
  const int lane = threadIdx.x;
  float a = 0.0f;
#pragma unroll
  for (int r = 0; r < NSLOT; ++r) a += ws[r * 64 + lane];  // 32 indep loads

  // n_masked = sum of ct_count columns (lanes 40..59), uniform collective
  const float n_masked =
      wave_reduce((lane >= 2 * NCLS && lane < 3 * NCLS) ? a : 0.0f);

  // LDS bounce for per-class gather — NO divergent cross-lane ops
  s[lane] = a;
  __syncthreads();

  float loss = 0.0f, validf = 0.0f;
  if (lane < NCLS) {
    const float sump = s[lane];
    const float nom = s[NCLS + lane];
    const float cnt = s[2 * NCLS + lane];
    const bool valid = cnt > 0.0f;
    const float prec = nom / fmaxf(sump, 1e-38f);
    const float rec = nom / fmaxf(cnt, 1.0f);
    const float negc = n_masked - cnt;
    const float specn = n_masked - sump - cnt + nom;
    const float spec = specn / fmaxf(negc, 1.0f);
    loss = neg_log_clamped(prec, valid && (sump > 0.0f)) +
           neg_log_clamped(rec, valid) +
           neg_log_clamped(spec, valid && (negc > 0.0f));
    validf = valid ? 1.0f : 0.0f;
  }
  loss = wave_reduce(loss);      // uniform: all 64 lanes participate
  validf = wave_reduce(validf);
  if (lane == 0) out[0] = loss / validf;
}

extern "C" void kernel_launch(void* const* d_in, const int* in_sizes, int n_in,
                              void* d_out, int out_size, void* d_ws, size_t ws_size,
                              hipStream_t stream) {
  const float* pred = (const float*)d_in[0];
  const int* target = (const int*)d_in[1];
  const int N = in_sizes[1];  // voxel count; C = in_sizes[0]/N = 20
  const int npair = N >> 1;
  const int per_iter = NBLK * (NTHR >> 1);              // pairs per grid-iter
  const int iters = (npair + per_iter - 1) / per_iter;  // 4 for N = 2^21

  hipMemsetAsync(d_ws, 0, NSLOT * 64 * sizeof(float), stream);
  pass1<<<NBLK, NTHR, 0, stream>>>(pred, target, (float*)d_ws, N, iters);
  pass2<<<1, 64, 0, stream>>>((const float*)d_ws, (float*)d_out);
}